// Round 3
// baseline (173.078 us; speedup 1.0000x reference)
//
#include <hip/hip_runtime.h>
#include <hip/hip_bf16.h>

// TwoHotEmbedding: out[t] = w[i1[t]] + w[i2[t]], except out[t] = w[i1[t]] when i1==i2.
// One 64-lane wave handles 4 tokens (4 KB of output). Per token, lane i moves
// one float4 (16 B): 64 lanes x 16 B = one full 256-float row, coalesced.
// Batching 4 tokens/wave puts 8 independent 1KB gather loads in flight per wave
// (latency hiding for random L2-miss gathers); output uses nontemporal stores
// so the 67 MB write-once stream doesn't evict gather rows from L2.

#define EMBED_DIM 256
#define TOK_PER_WAVE 4

// clang native vector type — required by __builtin_nontemporal_store
// (HIP's float4 is a class and is rejected).
typedef float vf4 __attribute__((ext_vector_type(4)));

__global__ __launch_bounds__(256) void TwoHotEmbedding_13030930776069_kernel(
    const int* __restrict__ idx1,
    const int* __restrict__ idx2,
    const float* __restrict__ weight,
    float* __restrict__ out,
    int n_tokens)
{
    const int lane   = threadIdx.x & 63;
    const int waveId = (blockIdx.x * blockDim.x + threadIdx.x) >> 6;
    const int t0     = waveId * TOK_PER_WAVE;
    if (t0 >= n_tokens) return;

    // Wave-uniform index loads (compiler emits scalar loads).
    int a[TOK_PER_WAVE], b[TOK_PER_WAVE];
#pragma unroll
    for (int i = 0; i < TOK_PER_WAVE; ++i) {
        a[i] = idx1[t0 + i];
        b[i] = idx2[t0 + i];
    }

    // Issue all 8 gather loads before consuming any (max MLP).
    vf4 va[TOK_PER_WAVE], vb[TOK_PER_WAVE];
#pragma unroll
    for (int i = 0; i < TOK_PER_WAVE; ++i) {
        va[i] = ((const vf4*)(weight + (size_t)a[i] * EMBED_DIM))[lane];
        vb[i] = ((const vf4*)(weight + (size_t)b[i] * EMBED_DIM))[lane];
    }

#pragma unroll
    for (int i = 0; i < TOK_PER_WAVE; ++i) {
        vf4 r = (a[i] == b[i]) ? va[i]            // scatter-to-same-slot sets 1, not 2
                               : (va[i] + vb[i]);
        vf4* dst = (vf4*)(out + (size_t)(t0 + i) * EMBED_DIM) + lane;
        __builtin_nontemporal_store(r, dst);
    }
}

extern "C" void kernel_launch(void* const* d_in, const int* in_sizes, int n_in,
                              void* d_out, int out_size, void* d_ws, size_t ws_size,
                              hipStream_t stream) {
    const int*   idx1   = (const int*)d_in[0];    // input_one [16,4096] int32
    const int*   idx2   = (const int*)d_in[1];    // input_two [16,4096] int32
    const float* weight = (const float*)d_in[2];  // [100000,256] fp32
    float*       out    = (float*)d_out;          // [16,4096,256] fp32

    const int n_tokens = in_sizes[0];             // 65536
    // 4 waves/block x 4 tokens/wave = 16 tokens per 256-thread block
    const int tokens_per_block = 4 * TOK_PER_WAVE;
    const int blocks = (n_tokens + tokens_per_block - 1) / tokens_per_block;
    TwoHotEmbedding_13030930776069_kernel<<<blocks, 256, 0, stream>>>(
        idx1, idx2, weight, out, n_tokens);
}

// Round 4
// 168.915 us; speedup vs baseline: 1.0246x; 1.0246x over previous
//
#include <hip/hip_runtime.h>
#include <hip/hip_bf16.h>

// TwoHotEmbedding: out[t] = w[i1[t]] + w[i2[t]], except out[t] = w[i1[t]] when i1==i2.
// One 64-lane wave handles 8 tokens (8 KB of output). Per token, lane i moves
// one float4 (16 B): 64 lanes x 16 B = one full 256-float row, coalesced.
// 8 tokens/wave puts 16 independent 1KB gather loads in flight per wave
// (latency hiding for random L2/L3-miss gathers); output uses nontemporal
// stores so the 67 MB write-once stream doesn't evict gather rows from L2.

#define EMBED_DIM 256
#define TOK_PER_WAVE 8

// clang native vector type — required by __builtin_nontemporal_store
// (HIP's float4 is a class and is rejected).
typedef float vf4 __attribute__((ext_vector_type(4)));

__global__ __launch_bounds__(256) void TwoHotEmbedding_13030930776069_kernel(
    const int* __restrict__ idx1,
    const int* __restrict__ idx2,
    const float* __restrict__ weight,
    float* __restrict__ out,
    int n_tokens)
{
    const int lane   = threadIdx.x & 63;
    const int waveId = (blockIdx.x * blockDim.x + threadIdx.x) >> 6;
    // t0 is wave-uniform; readfirstlane makes that provable -> scalar idx loads.
    const int t0 = __builtin_amdgcn_readfirstlane(waveId * TOK_PER_WAVE);
    if (t0 >= n_tokens) return;

    int a[TOK_PER_WAVE], b[TOK_PER_WAVE];
#pragma unroll
    for (int i = 0; i < TOK_PER_WAVE; ++i) {
        a[i] = idx1[t0 + i];
        b[i] = idx2[t0 + i];
    }

    // Issue all 16 gather loads before consuming any (max MLP).
    vf4 va[TOK_PER_WAVE], vb[TOK_PER_WAVE];
#pragma unroll
    for (int i = 0; i < TOK_PER_WAVE; ++i) {
        va[i] = ((const vf4*)(weight + (size_t)a[i] * EMBED_DIM))[lane];
        vb[i] = ((const vf4*)(weight + (size_t)b[i] * EMBED_DIM))[lane];
    }

#pragma unroll
    for (int i = 0; i < TOK_PER_WAVE; ++i) {
        vf4 r = (a[i] == b[i]) ? va[i]            // scatter-to-same-slot sets 1, not 2
                               : (va[i] + vb[i]);
        vf4* dst = (vf4*)(out + (size_t)(t0 + i) * EMBED_DIM) + lane;
        __builtin_nontemporal_store(r, dst);
    }
}

extern "C" void kernel_launch(void* const* d_in, const int* in_sizes, int n_in,
                              void* d_out, int out_size, void* d_ws, size_t ws_size,
                              hipStream_t stream) {
    const int*   idx1   = (const int*)d_in[0];    // input_one [16,4096] int32
    const int*   idx2   = (const int*)d_in[1];    // input_two [16,4096] int32
    const float* weight = (const float*)d_in[2];  // [100000,256] fp32
    float*       out    = (float*)d_out;          // [16,4096,256] fp32

    const int n_tokens = in_sizes[0];             // 65536
    // 4 waves/block x 8 tokens/wave = 32 tokens per 256-thread block
    const int tokens_per_block = 4 * TOK_PER_WAVE;
    const int blocks = (n_tokens + tokens_per_block - 1) / tokens_per_block;
    TwoHotEmbedding_13030930776069_kernel<<<blocks, 256, 0, stream>>>(
        idx1, idx2, weight, out, n_tokens);
}